// Round 10
// baseline (228.018 us; speedup 1.0000x reference)
//
#include <hip/hip_runtime.h>
#include <hip/hip_bf16.h>
#include <stdint.h>

#define WIDTH 4096
#define NROWS 8192
#define NHEADS 8
#define BW 512
#define CS 128
#define NCHUNK (NROWS/CS)
#define LOG2E 1.4426950408889634f

typedef short bf16x8 __attribute__((ext_vector_type(8)));
typedef float f32x4 __attribute__((ext_vector_type(4)));

__device__ __forceinline__ uint32_t rne_bf16(float f) {
  uint32_t u = __float_as_uint(f);
  return (u + 0x7fffu + ((u >> 16) & 1u)) >> 16;
}
__device__ __forceinline__ uint32_t pack2(float lo, float hi) {
  return rne_bf16(lo) | (rne_bf16(hi) << 16);
}
__device__ __forceinline__ float bf16_to_f32(uint32_t bits) {
  return __uint_as_float(bits << 16);
}

__device__ __forceinline__ void gload_lds16(const void* g, void* l) {
  __builtin_amdgcn_global_load_lds(
      (const __attribute__((address_space(1))) void*)g,
      (__attribute__((address_space(3))) void*)l, 16, 0, 0);
}

// ---- prep: x f32 -> bf16 ----
__global__ void prep_xbf16(const float* __restrict__ x, uint16_t* __restrict__ xb) {
  size_t i = ((size_t)blockIdx.x * 256 + threadIdx.x) * 8;
  float4 f0 = *reinterpret_cast<const float4*>(x + i);
  float4 f1 = *reinterpret_cast<const float4*>(x + i + 4);
  uint4 v;
  v.x = pack2(f0.x, f0.y); v.y = pack2(f0.z, f0.w);
  v.z = pack2(f1.x, f1.y); v.w = pack2(f1.z, f1.w);
  *reinterpret_cast<uint4*>(xb + i) = v;
}

// ---- prep: transpose weights f32 [h][i][j] -> bf16 [g*8+h][j][i], ×log2e ----
__global__ void prep_weights(const float* __restrict__ ig_w,
                             const float* __restrict__ ag_w,
                             uint16_t* __restrict__ wt) {
  __shared__ float tile[32][33];
  int j0 = blockIdx.x * 32;
  int i0 = blockIdx.y * 32;
  int m  = blockIdx.z;  // g*8+h
  const float* src = ((m >> 3) ? ag_w : ig_w) + (size_t)(m & 7) * BW * BW;
  int tx = threadIdx.x & 31, ty = threadIdx.x >> 5;
  #pragma unroll
  for (int k = 0; k < 4; k++) {
    int i = i0 + ty + 8 * k;
    tile[ty + 8 * k][tx] = src[(size_t)i * BW + (j0 + tx)];
  }
  __syncthreads();
  #pragma unroll
  for (int k = 0; k < 4; k++) {
    int j = j0 + ty + 8 * k;
    wt[((size_t)m * BW + j) * BW + (i0 + tx)] =
        (uint16_t)rne_bf16(tile[tx][ty + 8 * k] * LOG2E);
  }
}

__global__ void prep_misc(const float* __restrict__ a_param, float* __restrict__ cvec2) {
  int i = blockIdx.x * 256 + threadIdx.x;
  if (i < WIDTH) {
    float x = a_param[i];
    float sp = (x > 15.f) ? x : log1pf(expf(x));
    cvec2[i] = 8.f * sp * LOG2E;   // log2-domain
  }
}

// ---- GEMM: dual-gate bf16 MFMA, tile 128x128, BK=64, 256 thr.
//      X: bf16, K-parity double-buffer (slice p -> half p&1); rotated K order
//      ends with slices 2nt (half0) & 2nt+1 (half1) resident for the epilogue.
//      W: single 32KB buffer. 64KB LDS -> 2 blocks/CU.
#define BM 128
#define BN 128
#define BK 64
// LDS: X half0 @0 (16KB), half1 @16384; W [2][128][64]bf16 @32768 (32KB);
//      resetm @65536 (128B). All rows 128B, chunk-swizzle ^((row&7)<<4).

__global__ __launch_bounds__(256, 2)
void gates_gemm(const uint16_t* __restrict__ xb,
                const int* __restrict__ s,
                const uint16_t* __restrict__ wt,
                const float* __restrict__ ig_b,
                const float* __restrict__ ag_b,
                const float* __restrict__ cvec2,
                uint32_t* __restrict__ lanx,
                float* __restrict__ cA,
                float* __restrict__ cB) {
  extern __shared__ __align__(16) unsigned char dsm[];   // 65664 B
  unsigned char* resetm = dsm + 65536;

  const int b = blockIdx.x;                    // 0..2047
  const int orig = (b & 7) * 256 + (b >> 3);   // XCD-chunked: one head per XCD
  const int h  = orig >> 8;
  const int rem = orig & 255;
  const int mt = rem >> 2;                     // 0..63
  const int nt = rem & 3;                      // 0..3
  const int m0 = mt * BM;
  const int j0 = nt * BN;

  const int tid = threadIdx.x;
  const int lane = tid & 63;
  const int w = tid >> 6;       // 0..3
  const int wr = w >> 1;        // 0..1 (M: 64-row halves)
  const int wc = w & 1;         // 0..1 (N: 64-col halves)
  const int lrow = lane & 15;
  const int lkg  = lane >> 4;

  if (tid < BM) {
    int n = m0 + tid;
    resetm[tid] = (n == 0) || (s[n] != s[n - 1]);
  }

  // X staging: source pre-swizzled per 16B chunk, LDS linear (per half)
  const char* xb_src[4];
  #pragma unroll
  for (int i = 0; i < 4; i++) {
    int o = i * 4096 + tid * 16;                   // [0,16384)
    int row = o >> 7;                              // 0..127
    int c = (o & 127) ^ ((row & 7) << 4);
    xb_src[i] = (const char*)xb + (size_t)(m0 + row) * (WIDTH * 2) + h * (BW * 2) + c;
  }
  // W staging: 32KB (both gates, 128 cols)
  const char* w_src[8];
  #pragma unroll
  for (int i = 0; i < 8; i++) {
    int o = i * 4096 + tid * 16;                   // [0,32768)
    int g = o >> 14;                               // 0..1
    int jl = (o >> 7) & 127;                       // 0..127
    int c = (o & 127) ^ ((jl & 7) << 4);
    w_src[i] = (const char*)wt + ((size_t)((g * 8 + h) * BW + (j0 + jl))) * (BW * 2) + c;
  }

  f32x4 acc[2][4][4];
  #pragma unroll
  for (int g = 0; g < 2; g++)
    #pragma unroll
    for (int mf = 0; mf < 4; mf++)
      #pragma unroll
      for (int nf = 0; nf < 4; nf++)
        acc[g][mf][nf] = (f32x4){0.f, 0.f, 0.f, 0.f};

  // prologue: stage X(p0)->half0, X(p1)->half1, W(p0)
  {
    const int p0 = (2 * nt + 2) & 7;
    const int p1 = (2 * nt + 3) & 7;
    #pragma unroll
    for (int i = 0; i < 4; i++)
      gload_lds16(xb_src[i] + p0 * 128, dsm + i * 4096 + tid * 16);
    #pragma unroll
    for (int i = 0; i < 4; i++)
      gload_lds16(xb_src[i] + p1 * 128, dsm + 16384 + i * 4096 + tid * 16);
    #pragma unroll
    for (int i = 0; i < 8; i++)
      gload_lds16(w_src[i] + p0 * 128, dsm + 32768 + i * 4096 + tid * 16);
  }
  __syncthreads();

  for (int kt = 0; kt < 8; kt++) {
    const uint32_t cbase = (uint32_t)(kt & 1) << 14;   // X half for this kt
    #pragma unroll
    for (int ks = 0; ks < 2; ks++) {
      bf16x8 af[4];
      #pragma unroll
      for (int mf = 0; mf < 4; mf++) {
        int row = wr * 64 + 16 * mf + lrow;
        uint32_t addr = cbase + (uint32_t)((row << 7) + ks * 64 + lkg * 16);
        addr ^= (uint32_t)((row & 7) << 4);
        af[mf] = *reinterpret_cast<const bf16x8*>(dsm + addr);
      }
      #pragma unroll
      for (int g = 0; g < 2; g++) {
        #pragma unroll
        for (int nf = 0; nf < 4; nf++) {
          int j = wc * 64 + 16 * nf + lrow;
          uint32_t addr = (uint32_t)(32768 + (g << 14) + (j << 7) + ks * 64 + lkg * 16);
          addr ^= (uint32_t)((j & 7) << 4);
          bf16x8 bfr = *reinterpret_cast<const bf16x8*>(dsm + addr);
          #pragma unroll
          for (int mf = 0; mf < 4; mf++) {
            acc[g][mf][nf] = __builtin_amdgcn_mfma_f32_16x16x32_bf16(
                af[mf], bfr, acc[g][mf][nf], 0, 0, 0);
          }
        }
      }
    }
    __syncthreads();   // all waves done reading W buf + X half(kt&1)
    if (kt < 7) {      // stage next W slice
      const int pw = (2 * nt + 3 + kt) & 7;
      #pragma unroll
      for (int i = 0; i < 8; i++)
        gload_lds16(w_src[i] + pw * 128, dsm + 32768 + i * 4096 + tid * 16);
    }
    if (kt < 6) {      // stage X slice kt+2 into the half just freed
      const int px = (2 * nt + 4 + kt) & 7;
      const uint32_t nb = cbase;
      #pragma unroll
      for (int i = 0; i < 4; i++)
        gload_lds16(xb_src[i] + px * 128, dsm + nb + i * 4096 + tid * 16);
    }
    __syncthreads();   // drain staging
  }
  // half0 = slice 2nt (cols j0..j0+63), half1 = slice 2nt+1 (cols j0+64..127).

  float* smf = (float*)(dsm + 32768);  // reuse W region: A[2][128], B[2][128]

  float igb[4], agb[4], cv2[4];
  #pragma unroll
  for (int nf = 0; nf < 4; nf++) {
    int jj = h * BW + j0 + wc * 64 + 16 * nf + lrow;
    igb[nf] = ig_b[jj] * LOG2E;
    agb[nf] = ag_b[jj] * LOG2E;
    cv2[nf] = cvec2[jj];
  }

  const uint32_t xhalf = (uint32_t)wc << 14;
  float segA[4][4], segB[4][4];   // [nf][mf]
  #pragma unroll
  for (int mf = 0; mf < 4; mf++) {
    float A[4] = {1.f, 1.f, 1.f, 1.f}, B[4] = {0.f, 0.f, 0.f, 0.f};
    int rbase = wr * 64 + 16 * mf + 4 * lkg;
    #pragma unroll
    for (int r = 0; r < 4; r++) {
      int row = rbase + r;
      int n = m0 + row;
      bool rs = resetm[row] != 0;
      uint32_t xswz = (uint32_t)((row & 7) << 4);
      #pragma unroll
      for (int nf = 0; nf < 4; nf++) {   // nf inner: 256B contiguous per row
        int cloc = 16 * nf + lrow;       // 0..63 within this wave's slice
        size_t o = (size_t)n * WIDTH + h * BW + j0 + wc * 64 + cloc;
        float yig = acc[0][mf][nf][r] + igb[nf];   // log2-domain
        float yag = acc[1][mf][nf][r] + agb[nf];
        float gx = __builtin_amdgcn_rcpf(1.f + exp2f(-yig));
        float ga = __builtin_amdgcn_rcpf(1.f + exp2f(-yag));
        float la2 = -ga * cv2[nf];
        uint32_t la_bits = rne_bf16(la2);
        float la_r = bf16_to_f32(la_bits);
        float a = exp2f(la_r);
        float mult = rs ? 1.f
                     : __builtin_amdgcn_sqrtf(fmaxf(1.f - a * a, 0.f));
        uint32_t xaddr = xhalf + (uint32_t)(row << 7) + (((uint32_t)(cloc * 2)) ^ xswz);
        float xv = bf16_to_f32(*reinterpret_cast<const uint16_t*>(dsm + xaddr));
        float nx = xv * gx * mult;
        uint32_t nx_bits = rne_bf16(nx);
        float nx_r = bf16_to_f32(nx_bits);
        lanx[o] = la_bits | (nx_bits << 16);
        A[nf] *= a;
        B[nf] = fmaf(a, B[nf], nx_r);
      }
    }
    #pragma unroll
    for (int nf = 0; nf < 4; nf++) { segA[nf][mf] = A[nf]; segB[nf][mf] = B[nf]; }
  }
  // combine across lkg (stride-16 lanes, order = lkg ascending), then mf
  #pragma unroll
  for (int nf = 0; nf < 4; nf++) {
    #pragma unroll
    for (int mf = 0; mf < 4; mf++) {
      float A = segA[nf][mf], B = segB[nf][mf];
      #pragma unroll
      for (int d = 16; d <= 32; d <<= 1) {
        float pA = __shfl_xor(A, d, 64);
        float pB = __shfl_xor(B, d, 64);
        bool up = (lane & d) != 0;
        B = up ? fmaf(A, pB, B) : fmaf(pA, B, pB);
        A *= pA;
      }
      segA[nf][mf] = A; segB[nf][mf] = B;
    }
    float colA = segA[nf][0], colB = segB[nf][0];
    #pragma unroll
    for (int mf = 1; mf < 4; mf++) {
      colB = fmaf(segA[nf][mf], colB, segB[nf][mf]);
      colA *= segA[nf][mf];
    }
    if (lkg == 0) {
      int clocal = wc * 64 + 16 * nf + lrow;     // 0..127
      smf[wr * 128 + clocal] = colA;
      smf[256 + wr * 128 + clocal] = colB;
    }
  }
  __syncthreads();
  if (tid < BN) {
    float A0 = smf[tid],        B0 = smf[256 + tid];
    float A1 = smf[128 + tid],  B1 = smf[384 + tid];
    float Af = A0 * A1;
    float Bf = fmaf(A1, B0, B1);
    int jj = h * BW + j0 + tid;
    cA[mt * WIDTH + jj] = Af;   // chunk index == mt (BM == CS)
    cB[mt * WIDTH + jj] = Bf;
  }
}

// ---- scan phase B: prefix over chunks ----
__global__ void scan_prefix(const float* __restrict__ cA, const float* __restrict__ cB,
                            float* __restrict__ prefix) {
  int c = blockIdx.x * 256 + threadIdx.x;
  float hcur = 0.f;
  for (int i0 = 0; i0 < NCHUNK; i0 += 8) {
    float av[8], bv[8];
    #pragma unroll
    for (int e = 0; e < 8; e++) { av[e] = cA[(i0 + e) * WIDTH + c]; bv[e] = cB[(i0 + e) * WIDTH + c]; }
    #pragma unroll
    for (int e = 0; e < 8; e++) { prefix[(i0 + e) * WIDTH + c] = hcur; hcur = av[e] * hcur + bv[e]; }
  }
}

// ---- scan phase C: apply (packed la2|nx in, f32 out; a = exp2(la2)) ----
__global__ void scan_apply(const uint32_t* __restrict__ lanx,
                           const float* __restrict__ prefix,
                           float* __restrict__ out) {
  int chunk = blockIdx.x;
  int c0 = (blockIdx.y * 256 + threadIdx.x) * 4;
  size_t base = (size_t)chunk * CS * WIDTH + c0;
  float h[4];
  #pragma unroll
  for (int q = 0; q < 4; q++) h[q] = prefix[chunk * WIDTH + c0 + q];
  for (int rb = 0; rb < CS; rb += 4) {
    uint4 v[4];
    #pragma unroll
    for (int e = 0; e < 4; e++)
      v[e] = *reinterpret_cast<const uint4*>(lanx + base + (size_t)(rb + e) * WIDTH);
    #pragma unroll
    for (int e = 0; e < 4; e++) {
      float4 ov;
      h[0] = fmaf(exp2f(bf16_to_f32(v[e].x & 0xffffu)), h[0], bf16_to_f32(v[e].x >> 16)); ov.x = h[0];
      h[1] = fmaf(exp2f(bf16_to_f32(v[e].y & 0xffffu)), h[1], bf16_to_f32(v[e].y >> 16)); ov.y = h[1];
      h[2] = fmaf(exp2f(bf16_to_f32(v[e].z & 0xffffu)), h[2], bf16_to_f32(v[e].z >> 16)); ov.z = h[2];
      h[3] = fmaf(exp2f(bf16_to_f32(v[e].w & 0xffffu)), h[3], bf16_to_f32(v[e].w >> 16)); ov.w = h[3];
      *reinterpret_cast<float4*>(out + base + (size_t)(rb + e) * WIDTH) = ov;
    }
  }
}

extern "C" void kernel_launch(void* const* d_in, const int* in_sizes, int n_in,
                              void* d_out, int out_size, void* d_ws, size_t ws_size,
                              hipStream_t stream) {
  const float* x       = (const float*)d_in[0];
  const int*   s       = (const int*)d_in[1];
  const float* a_param = (const float*)d_in[2];
  const float* ig_w    = (const float*)d_in[3];
  const float* ig_b    = (const float*)d_in[4];
  const float* ag_w    = (const float*)d_in[5];
  const float* ag_b    = (const float*)d_in[6];
  float* out = (float*)d_out;
  char* ws = (char*)d_ws;

  uint32_t* lanx   = (uint32_t*)ws;                     // 134217728 B
  uint16_t* wt     = (uint16_t*)(ws + 134217728);       //   8388608 B
  uint16_t* xb     = (uint16_t*)(ws + 142606336);       //  67108864 B
  float*    cvec2  = (float*)(ws + 209715200);          //     16384 B
  float*    cA     = (float*)(ws + 209731584);          //   1048576 B
  float*    cB     = (float*)(ws + 210780160);          //   1048576 B
  float*    prefix = (float*)(ws + 211828736);          //   1048576 B

  prep_xbf16<<<dim3(16384), 256, 0, stream>>>(x, xb);
  prep_weights<<<dim3(16, 16, 16), 256, 0, stream>>>(ig_w, ag_w, wt);
  prep_misc<<<dim3(16), 256, 0, stream>>>(a_param, cvec2);
  gates_gemm<<<dim3(2048), dim3(256), 65664, stream>>>(xb, s, wt, ig_b, ag_b, cvec2,
                                                       lanx, cA, cB);
  scan_prefix<<<dim3(16), 256, 0, stream>>>(cA, cB, prefix);
  scan_apply<<<dim3(NCHUNK, 4), 256, 0, stream>>>(lanx, prefix, out);
}